// Round 1
// baseline (589.549 us; speedup 1.0000x reference)
//
#include <hip/hip_runtime.h>
#include <math.h>

#define L 13
#define L3 2197            // 13^3
#define NT 256

// LDS ping-pong sizes: A holds stages 13^3 / 13*13*17->no wait:
// stage sizes: 2197 -> 2873 -> 3757 -> 4913 -> 3757 -> 2873 -> 2197
// A holds stages 0,2,4,6 (max 3757); B holds stages 1,3,5 (max 4913).
#define ASZ 3757
#define BSZ 4913

__device__ __forceinline__ int clamp13(int v) {
    return min(max(v, 0), 12);
}

// A holds 13^3 input ([a][b][c], c contiguous). On return A holds 13^3 smooth(A).
// smooth = edge-pad(3) -> maxpool3 -> avgpool3 -> avgpool3  (all separable)
__device__ void smooth_inplace(float* A, float* B, int tid) {
    __syncthreads();
    // M1: max along c with clamp: (13,13,13) -> (13,13,17), A -> B
    for (int idx = tid; idx < 13 * 13 * 17; idx += NT) {
        int c = idx % 17;
        int ab = idx / 17;
        const float* row = A + ab * 13;
        int c0 = c - 3;
        float m = row[clamp13(c0)];
        m = fmaxf(m, row[clamp13(c0 + 1)]);
        m = fmaxf(m, row[clamp13(c0 + 2)]);
        B[idx] = m;
    }
    __syncthreads();
    // M2: max along b: (13,13,17) -> (13,17,17), B -> A
    for (int idx = tid; idx < 13 * 17 * 17; idx += NT) {
        int c = idx % 17;
        int t = idx / 17;
        int b = t % 17;
        int a = t / 17;
        const float* pl = B + a * (13 * 17) + c;
        int b0 = b - 3;
        float m = pl[clamp13(b0) * 17];
        m = fmaxf(m, pl[clamp13(b0 + 1) * 17]);
        m = fmaxf(m, pl[clamp13(b0 + 2) * 17]);
        A[idx] = m;
    }
    __syncthreads();
    // M3: max along a: (13,17,17) -> (17,17,17), A -> B
    for (int idx = tid; idx < 17 * 17 * 17; idx += NT) {
        int bc = idx % (17 * 17);
        int a = idx / (17 * 17);
        const float* pl = A + bc;
        int a0 = a - 3;
        float m = pl[clamp13(a0) * 289];
        m = fmaxf(m, pl[clamp13(a0 + 1) * 289]);
        m = fmaxf(m, pl[clamp13(a0 + 2) * 289]);
        B[idx] = m;
    }
    __syncthreads();
    // C1: triangle conv [1,2,3,2,1] along c: (17,17,17) -> (17,17,13), B -> A
    for (int idx = tid; idx < 17 * 17 * 13; idx += NT) {
        int c = idx % 13;
        int ab = idx / 13;
        const float* p = B + ab * 17 + c;
        A[idx] = p[0] + 2.0f * p[1] + 3.0f * p[2] + 2.0f * p[3] + p[4];
    }
    __syncthreads();
    // C2: conv along b: (17,17,13) -> (17,13,13), A -> B
    for (int idx = tid; idx < 17 * 13 * 13; idx += NT) {
        int c = idx % 13;
        int t = idx / 13;
        int b = t % 13;
        int a = t / 13;
        const float* p = A + (a * 17 + b) * 13 + c;
        B[idx] = p[0] + 2.0f * p[13] + 3.0f * p[26] + 2.0f * p[39] + p[52];
    }
    __syncthreads();
    // C3: conv along a: (17,13,13) -> (13,13,13), B -> A, apply 1/729
    for (int idx = tid; idx < 13 * 13 * 13; idx += NT) {
        int bc = idx % 169;
        int a = idx / 169;
        const float* p = B + a * 169 + bc;
        A[idx] = (p[0] + 2.0f * p[169] + 3.0f * p[338] + 2.0f * p[507] + p[676])
                 * (1.0f / 729.0f);
    }
    __syncthreads();
}

__global__ __launch_bounds__(NT) void k_smooth1(
        const float* __restrict__ cost, const float* __restrict__ alpha,
        float* __restrict__ tmp1) {
    __shared__ float A[ASZ];
    __shared__ float B[BSZ];
    const int n = blockIdx.x;
    const int tid = threadIdx.x;
    const float a0 = alpha[0], a1 = alpha[1];
    const float* src = cost + (size_t)n * L3;
    for (int i = tid; i < L3; i += NT) A[i] = a1 + a0 * src[i];
    smooth_inplace(A, B, tid);
    float* dst = tmp1 + (size_t)n * L3;
    for (int i = tid; i < L3; i += NT) dst[i] = A[i];
}

__global__ __launch_bounds__(NT) void k_mid(
        const float* __restrict__ cost, const int* __restrict__ knn,
        const float* __restrict__ dist, const float* __restrict__ alpha,
        const float* __restrict__ tmp1, float* __restrict__ tmp2, int K) {
    __shared__ float A[ASZ];
    __shared__ float B[BSZ];
    __shared__ float s_w[8];
    const int n = blockIdx.x;
    const int tid = threadIdx.x;
    if (tid < K) s_w[tid] = expf(-dist[n * K + tid] * (1.0f / 200.0f));
    __syncthreads();
    float norm = 0.0f;
    for (int k = 0; k < K; ++k) norm += s_w[k];
    const float a0 = alpha[0], a1 = alpha[1], a2 = alpha[2];
    const float a3 = alpha[3], a4 = alpha[4];
    const float sc = a3 / norm;

    const float* ptr[8];
    float wk[8];
    for (int k = 0; k < K; ++k) {
        ptr[k] = tmp1 + (size_t)knn[n * K + k] * L3;
        wk[k] = s_w[k];
    }
    const float* src = cost + (size_t)n * L3;
    for (int i = tid; i < L3; i += NT) {
        float acc = 0.0f;
        #pragma unroll 8
        for (int k = 0; k < K; ++k) acc += wk[k] * ptr[k][i];
        A[i] = a4 + a2 * (a1 + a0 * src[i]) + sc * acc;
    }
    smooth_inplace(A, B, tid);
    float* dst = tmp2 + (size_t)n * L3;
    for (int i = tid; i < L3; i += NT) dst[i] = A[i];
}

__global__ __launch_bounds__(NT) void k_out(
        const int* __restrict__ knn, const float* __restrict__ dist,
        const float* __restrict__ alpha, const float* __restrict__ tmp2,
        float* __restrict__ out, int K) {
    __shared__ float s_w[8];
    const int n = blockIdx.x;
    const int tid = threadIdx.x;
    if (tid < K) s_w[tid] = expf(-dist[n * K + tid] * (1.0f / 200.0f));
    __syncthreads();
    float norm = 0.0f;
    for (int k = 0; k < K; ++k) norm += s_w[k];
    const float a5 = alpha[5];
    const float sc = a5 / norm;

    const float* ptr[8];
    float wk[8];
    for (int k = 0; k < K; ++k) {
        ptr[k] = tmp2 + (size_t)knn[n * K + k] * L3;
        wk[k] = s_w[k];
    }
    float* dst = out + (size_t)n * L3;
    for (int i = tid; i < L3; i += NT) {
        float acc = 0.0f;
        #pragma unroll 8
        for (int k = 0; k < K; ++k) acc += wk[k] * ptr[k][i];
        dst[i] = sc * acc;
    }
}

extern "C" void kernel_launch(void* const* d_in, const int* in_sizes, int n_in,
                              void* d_out, int out_size, void* d_ws, size_t ws_size,
                              hipStream_t stream) {
    const float* cost  = (const float*)d_in[0];
    const int*   knn   = (const int*)d_in[1];
    const float* dist  = (const float*)d_in[2];
    const float* alpha = (const float*)d_in[3];
    float* out = (float*)d_out;

    const int N = in_sizes[0] / L3;
    int K = in_sizes[1] / N;
    if (K > 8) K = 8;

    float* tmp1 = (float*)d_ws;
    float* tmp2 = tmp1 + (size_t)N * L3;

    k_smooth1<<<N, NT, 0, stream>>>(cost, alpha, tmp1);
    k_mid<<<N, NT, 0, stream>>>(cost, knn, dist, alpha, tmp1, tmp2, K);
    k_out<<<N, NT, 0, stream>>>(knn, dist, alpha, tmp2, out, K);
}

// Round 2
// 450.245 us; speedup vs baseline: 1.3094x; 1.3094x over previous
//
#include <hip/hip_runtime.h>
#include <math.h>

#define L 13
#define L3 2197            // 13^3
#define SPAD 2200          // padded volume stride (16B-aligned: 2200*4 = 8800)
#define NT 256

// LDS ping-pong: stage sizes 2197 -> 2873 -> 3757 -> 4913 -> 3757 -> 2873 -> 2197
// A holds stages 0,2,4,6 (max 3757); B holds stages 1,3,5 (max 4913).
#define ASZ 3760
#define BSZ 4916

// Sliding clamped max-of-3: in x[13] (registers), out o[17].
// o[j] = max(x[cl(j-3)], x[cl(j-2)], x[cl(j-1)]), cl = clamp to [0,12]
__device__ __forceinline__ void maxpool_row(const float* x, float* o) {
    float p[12];
#pragma unroll
    for (int i = 0; i < 12; ++i) p[i] = fmaxf(x[i], x[i + 1]);
    o[0] = x[0];
    o[1] = x[0];
    o[2] = p[0];
#pragma unroll
    for (int j = 3; j <= 13; ++j) o[j] = fmaxf(p[j - 3], x[j - 1]);
    o[14] = p[11];
    o[15] = x[12];
    o[16] = x[12];
}

// Two stacked avgpool3 == 5-tap triangle [1,2,3,2,1]/9 per axis.
// in y[17], out o[13], scale applied (1.0 for first two axes, 1/729 last).
__device__ __forceinline__ void tri_row(const float* y, float* o, float scale) {
#pragma unroll
    for (int c = 0; c < 13; ++c) {
        float s = fmaf(2.0f, y[c + 1], y[c]);
        s = fmaf(3.0f, y[c + 2], s);
        s = fmaf(2.0f, y[c + 3], s);
        s = (s + y[c + 4]) * scale;
        o[c] = s;
    }
}

// A holds (13,13,13) input. On return A[0..2196] holds smooth(A).
// smooth = edge-pad(3) -> maxpool3 -> avgpool3 -> avgpool3 (separable).
__device__ void smooth_inplace(float* A, float* B, int tid) {
    __syncthreads();
    // M1 along c: A(13,13,13) -> B(13,13,17); 169 pencils
    if (tid < 169) {
        float x[13], o[17];
        const float* src = A + tid * 13;
#pragma unroll
        for (int i = 0; i < 13; ++i) x[i] = src[i];
        maxpool_row(x, o);
        float* dst = B + tid * 17;
#pragma unroll
        for (int i = 0; i < 17; ++i) dst[i] = o[i];
    }
    __syncthreads();
    // M2 along b: B(13,13,17) -> A(13,17,17); pencil (a,c), 221
    if (tid < 221) {
        int a = tid / 17, c = tid % 17;
        float x[13], o[17];
        const float* src = B + a * 221 + c;
#pragma unroll
        for (int i = 0; i < 13; ++i) x[i] = src[i * 17];
        maxpool_row(x, o);
        float* dst = A + a * 289 + c;
#pragma unroll
        for (int i = 0; i < 17; ++i) dst[i * 17] = o[i];
    }
    __syncthreads();
    // M3 along a: A(13,17,17) -> B(17,17,17); pencil (b,c), 289
    for (int p = tid; p < 289; p += NT) {
        float x[13], o[17];
        const float* src = A + p;
#pragma unroll
        for (int i = 0; i < 13; ++i) x[i] = src[i * 289];
        maxpool_row(x, o);
        float* dst = B + p;
#pragma unroll
        for (int i = 0; i < 17; ++i) dst[i * 289] = o[i];
    }
    __syncthreads();
    // C1 along c: B(17,17,17) -> A(17,17,13); pencil (a,b), 289
    for (int p = tid; p < 289; p += NT) {
        float y[17], o[13];
        const float* src = B + p * 17;
#pragma unroll
        for (int i = 0; i < 17; ++i) y[i] = src[i];
        tri_row(y, o, 1.0f);
        float* dst = A + p * 13;
#pragma unroll
        for (int i = 0; i < 13; ++i) dst[i] = o[i];
    }
    __syncthreads();
    // C2 along b: A(17,17,13) -> B(17,13,13); pencil (a,c), 221
    if (tid < 221) {
        int a = tid / 13, c = tid % 13;
        float y[17], o[13];
        const float* src = A + a * 221 + c;
#pragma unroll
        for (int i = 0; i < 17; ++i) y[i] = src[i * 13];
        tri_row(y, o, 1.0f);
        float* dst = B + a * 169 + c;
#pragma unroll
        for (int i = 0; i < 13; ++i) dst[i * 13] = o[i];
    }
    __syncthreads();
    // C3 along a: B(17,13,13) -> A(13,13,13); pencil (b,c), 169
    if (tid < 169) {
        float y[17], o[13];
        const float* src = B + tid;
#pragma unroll
        for (int i = 0; i < 17; ++i) y[i] = src[i * 169];
        tri_row(y, o, 1.0f / 729.0f);
        float* dst = A + tid;
#pragma unroll
        for (int i = 0; i < 13; ++i) dst[i * 169] = o[i];
    }
    __syncthreads();
}

__global__ __launch_bounds__(NT) void k_smooth1(
        const float* __restrict__ cost, const float* __restrict__ alpha,
        float* __restrict__ tmp1, int S) {
    __shared__ alignas(16) float A[ASZ];
    __shared__ alignas(16) float B[BSZ];
    const int n = blockIdx.x;
    const int tid = threadIdx.x;
    const float a0 = alpha[0], a1 = alpha[1];
    const float* src = cost + (size_t)n * L3;   // input always stride L3
    for (int i = tid; i < L3; i += NT) A[i] = fmaf(a0, src[i], a1);
    smooth_inplace(A, B, tid);
    float* dst = tmp1 + (size_t)n * S;
    if ((S & 3) == 0) {
        // vector store incl. pad elems (A[2197..2199] = stale but deterministic)
        float4* d4 = (float4*)dst;
        const float4* a4 = (const float4*)A;
        for (int i = tid; i < S / 4; i += NT) d4[i] = a4[i];
    } else {
        for (int i = tid; i < L3; i += NT) dst[i] = A[i];
    }
}

__global__ __launch_bounds__(NT) void k_mid(
        const float* __restrict__ cost, const int* __restrict__ knn,
        const float* __restrict__ dist, const float* __restrict__ alpha,
        const float* __restrict__ tmp1, float* __restrict__ tmp2, int K, int S) {
    __shared__ alignas(16) float A[ASZ];
    __shared__ alignas(16) float B[BSZ];
    __shared__ float s_w[8];
    const int n = blockIdx.x;
    const int tid = threadIdx.x;
    if (tid < K) s_w[tid] = expf(-dist[n * K + tid] * (1.0f / 200.0f));
    __syncthreads();
    float norm = 0.0f;
    for (int k = 0; k < K; ++k) norm += s_w[k];
    const float a0 = alpha[0], a1 = alpha[1], a2 = alpha[2];
    const float a3 = alpha[3], a4 = alpha[4];
    const float sc = a3 / norm;

    const float* ptr[8];
    float wk[8];
    for (int k = 0; k < K; ++k) {
        ptr[k] = tmp1 + (size_t)knn[n * K + k] * S;
        wk[k] = s_w[k];
    }
    const float* src = cost + (size_t)n * L3;
    // pass 1: affine of own cost (scalar coalesced; cost base not 16B-aligned)
    for (int i = tid; i < L3; i += NT) A[i] = fmaf(a2, fmaf(a0, src[i], a1), a4);
    __syncthreads();
    // pass 2: += weighted neighbor gather
    if ((S & 3) == 0) {
        float4* A4 = (float4*)A;
        for (int i = tid; i < S / 4; i += NT) {
            float4 acc = make_float4(0.f, 0.f, 0.f, 0.f);
#pragma unroll 8
            for (int k = 0; k < K; ++k) {
                float4 v = ((const float4*)ptr[k])[i];
                acc.x = fmaf(wk[k], v.x, acc.x);
                acc.y = fmaf(wk[k], v.y, acc.y);
                acc.z = fmaf(wk[k], v.z, acc.z);
                acc.w = fmaf(wk[k], v.w, acc.w);
            }
            float4 av = A4[i];
            av.x = fmaf(sc, acc.x, av.x);
            av.y = fmaf(sc, acc.y, av.y);
            av.z = fmaf(sc, acc.z, av.z);
            av.w = fmaf(sc, acc.w, av.w);
            A4[i] = av;
        }
    } else {
        for (int i = tid; i < L3; i += NT) {
            float acc = 0.0f;
#pragma unroll 8
            for (int k = 0; k < K; ++k) acc = fmaf(wk[k], ptr[k][i], acc);
            A[i] = fmaf(sc, acc, A[i]);
        }
    }
    smooth_inplace(A, B, tid);
    float* dst = tmp2 + (size_t)n * S;
    if ((S & 3) == 0) {
        float4* d4 = (float4*)dst;
        const float4* a4 = (const float4*)A;
        for (int i = tid; i < S / 4; i += NT) d4[i] = a4[i];
    } else {
        for (int i = tid; i < L3; i += NT) dst[i] = A[i];
    }
}

__global__ __launch_bounds__(NT) void k_out(
        const int* __restrict__ knn, const float* __restrict__ dist,
        const float* __restrict__ alpha, const float* __restrict__ tmp2,
        float* __restrict__ out, int K, int S) {
    __shared__ float s_w[8];
    const int n = blockIdx.x;
    const int tid = threadIdx.x;
    if (tid < K) s_w[tid] = expf(-dist[n * K + tid] * (1.0f / 200.0f));
    __syncthreads();
    float norm = 0.0f;
    for (int k = 0; k < K; ++k) norm += s_w[k];
    const float sc = alpha[5] / norm;

    const float* ptr[8];
    float wk[8];
    for (int k = 0; k < K; ++k) {
        ptr[k] = tmp2 + (size_t)knn[n * K + k] * S;
        wk[k] = s_w[k];
    }
    float* dst = out + (size_t)n * L3;   // output always stride L3 (no pad!)
    if ((S & 3) == 0) {
        for (int i = tid; i * 4 < L3; i += NT) {
            float4 acc = make_float4(0.f, 0.f, 0.f, 0.f);
#pragma unroll 8
            for (int k = 0; k < K; ++k) {
                float4 v = ((const float4*)ptr[k])[i];
                acc.x = fmaf(wk[k], v.x, acc.x);
                acc.y = fmaf(wk[k], v.y, acc.y);
                acc.z = fmaf(wk[k], v.z, acc.z);
                acc.w = fmaf(wk[k], v.w, acc.w);
            }
            int base = i * 4;
            dst[base] = sc * acc.x;
            if (base + 1 < L3) dst[base + 1] = sc * acc.y;
            if (base + 2 < L3) dst[base + 2] = sc * acc.z;
            if (base + 3 < L3) dst[base + 3] = sc * acc.w;
        }
    } else {
        for (int i = tid; i < L3; i += NT) {
            float acc = 0.0f;
#pragma unroll 8
            for (int k = 0; k < K; ++k) acc = fmaf(wk[k], ptr[k][i], acc);
            dst[i] = sc * acc;
        }
    }
}

extern "C" void kernel_launch(void* const* d_in, const int* in_sizes, int n_in,
                              void* d_out, int out_size, void* d_ws, size_t ws_size,
                              hipStream_t stream) {
    const float* cost  = (const float*)d_in[0];
    const int*   knn   = (const int*)d_in[1];
    const float* dist  = (const float*)d_in[2];
    const float* alpha = (const float*)d_in[3];
    float* out = (float*)d_out;

    const int N = in_sizes[0] / L3;
    int K = in_sizes[1] / N;
    if (K > 8) K = 8;

    // Padded stride if workspace allows (16B-aligned volume bases -> float4 gather)
    int S = (ws_size >= (size_t)2 * N * SPAD * sizeof(float)) ? SPAD : L3;

    float* tmp1 = (float*)d_ws;
    float* tmp2 = tmp1 + (size_t)N * S;

    k_smooth1<<<N, NT, 0, stream>>>(cost, alpha, tmp1, S);
    k_mid<<<N, NT, 0, stream>>>(cost, knn, dist, alpha, tmp1, tmp2, K, S);
    k_out<<<N, NT, 0, stream>>>(knn, dist, alpha, tmp2, out, K, S);
}

// Round 3
// 359.788 us; speedup vs baseline: 1.6386x; 1.2514x over previous
//
#include <hip/hip_runtime.h>
#include <math.h>

#define L3 2197            // 13^3
#define SP 2200            // bf16 elems per padded volume (4400 B, 16B-aligned)
#define NV (SP / 8)        // 275 uint4 chunks of 8 bf16
#define NT 256

// LDS ping-pong: stage sizes 2197 -> 2873 -> 3757 -> 4913 -> 3757 -> 2873 -> 2197
#define ASZ 3760
#define BSZ 4916

typedef unsigned int u32;

// round-to-nearest-even bf16 pack of two floats -> one u32 (lo = a, hi = b)
__device__ __forceinline__ u32 pack2bf(float a, float b) {
    u32 ua = __float_as_uint(a);
    u32 ub = __float_as_uint(b);
    ua = (ua + 0x7fffu + ((ua >> 16) & 1u)) >> 16;
    ub = (ub + 0x7fffu + ((ub >> 16) & 1u)) & 0xffff0000u;
    return ua | ub;
}

__device__ __forceinline__ void unpack8(uint4 v, float* f) {
    f[0] = __uint_as_float(v.x << 16);
    f[1] = __uint_as_float(v.x & 0xffff0000u);
    f[2] = __uint_as_float(v.y << 16);
    f[3] = __uint_as_float(v.y & 0xffff0000u);
    f[4] = __uint_as_float(v.z << 16);
    f[5] = __uint_as_float(v.z & 0xffff0000u);
    f[6] = __uint_as_float(v.w << 16);
    f[7] = __uint_as_float(v.w & 0xffff0000u);
}

__device__ __forceinline__ uint4 pack8(const float* f) {
    uint4 v;
    v.x = pack2bf(f[0], f[1]);
    v.y = pack2bf(f[2], f[3]);
    v.z = pack2bf(f[4], f[5]);
    v.w = pack2bf(f[6], f[7]);
    return v;
}

// Sliding clamped max-of-3: in x[13], out o[17].
__device__ __forceinline__ void maxpool_row(const float* x, float* o) {
    float p[12];
#pragma unroll
    for (int i = 0; i < 12; ++i) p[i] = fmaxf(x[i], x[i + 1]);
    o[0] = x[0];
    o[1] = x[0];
    o[2] = p[0];
#pragma unroll
    for (int j = 3; j <= 13; ++j) o[j] = fmaxf(p[j - 3], x[j - 1]);
    o[14] = p[11];
    o[15] = x[12];
    o[16] = x[12];
}

// Two stacked avgpool3 == 5-tap triangle [1,2,3,2,1]/9 per axis.
__device__ __forceinline__ void tri_row(const float* y, float* o, float scale) {
#pragma unroll
    for (int c = 0; c < 13; ++c) {
        float s = fmaf(2.0f, y[c + 1], y[c]);
        s = fmaf(3.0f, y[c + 2], s);
        s = fmaf(2.0f, y[c + 3], s);
        o[c] = (s + y[c + 4]) * scale;
    }
}

// A holds (13,13,13) input; on return A[0..2196] = smooth(A).
__device__ void smooth_inplace(float* A, float* B, int tid) {
    __syncthreads();
    // M1 along c: A(13,13,13) -> B(13,13,17)
    if (tid < 169) {
        float x[13], o[17];
        const float* src = A + tid * 13;
#pragma unroll
        for (int i = 0; i < 13; ++i) x[i] = src[i];
        maxpool_row(x, o);
        float* dst = B + tid * 17;
#pragma unroll
        for (int i = 0; i < 17; ++i) dst[i] = o[i];
    }
    __syncthreads();
    // M2 along b: B(13,13,17) -> A(13,17,17)
    if (tid < 221) {
        int a = tid / 17, c = tid % 17;
        float x[13], o[17];
        const float* src = B + a * 221 + c;
#pragma unroll
        for (int i = 0; i < 13; ++i) x[i] = src[i * 17];
        maxpool_row(x, o);
        float* dst = A + a * 289 + c;
#pragma unroll
        for (int i = 0; i < 17; ++i) dst[i * 17] = o[i];
    }
    __syncthreads();
    // M3 along a: A(13,17,17) -> B(17,17,17)
    for (int p = tid; p < 289; p += NT) {
        float x[13], o[17];
        const float* src = A + p;
#pragma unroll
        for (int i = 0; i < 13; ++i) x[i] = src[i * 289];
        maxpool_row(x, o);
        float* dst = B + p;
#pragma unroll
        for (int i = 0; i < 17; ++i) dst[i * 289] = o[i];
    }
    __syncthreads();
    // C1 along c: B(17,17,17) -> A(17,17,13)
    for (int p = tid; p < 289; p += NT) {
        float y[17], o[13];
        const float* src = B + p * 17;
#pragma unroll
        for (int i = 0; i < 17; ++i) y[i] = src[i];
        tri_row(y, o, 1.0f);
        float* dst = A + p * 13;
#pragma unroll
        for (int i = 0; i < 13; ++i) dst[i] = o[i];
    }
    __syncthreads();
    // C2 along b: A(17,17,13) -> B(17,13,13)
    if (tid < 221) {
        int a = tid / 13, c = tid % 13;
        float y[17], o[13];
        const float* src = A + a * 221 + c;
#pragma unroll
        for (int i = 0; i < 17; ++i) y[i] = src[i * 13];
        tri_row(y, o, 1.0f);
        float* dst = B + a * 169 + c;
#pragma unroll
        for (int i = 0; i < 13; ++i) dst[i * 13] = o[i];
    }
    __syncthreads();
    // C3 along a: B(17,13,13) -> A(13,13,13), apply 1/729
    if (tid < 169) {
        float y[17], o[13];
        const float* src = B + tid;
#pragma unroll
        for (int i = 0; i < 17; ++i) y[i] = src[i * 169];
        tri_row(y, o, 1.0f / 729.0f);
        float* dst = A + tid;
#pragma unroll
        for (int i = 0; i < 13; ++i) dst[i * 169] = o[i];
    }
    __syncthreads();
}

// tmp1 = smooth(affine) as bf16; preA = a4 + a2*affine as bf16
__global__ __launch_bounds__(NT) void k_smooth1(
        const float* __restrict__ cost, const float* __restrict__ alpha,
        uint4* __restrict__ tmp1, uint4* __restrict__ preA) {
    __shared__ alignas(16) float A[ASZ];
    __shared__ alignas(16) float B[BSZ];
    const int n = blockIdx.x;
    const int tid = threadIdx.x;
    const float a0 = alpha[0], a1 = alpha[1], a2 = alpha[2], a4 = alpha[4];
    const float* src = cost + (size_t)n * L3;
    for (int i = tid; i < L3; i += NT) A[i] = fmaf(a0, src[i], a1);
    if (tid < SP - L3) A[L3 + tid] = 0.0f;   // pad
    __syncthreads();
    uint4* pre = preA + (size_t)n * NV;
    for (int i = tid; i < NV; i += NT) {
        float f[8];
#pragma unroll
        for (int j = 0; j < 8; ++j) f[j] = fmaf(a2, A[8 * i + j], a4);
        pre[i] = pack8(f);
    }
    smooth_inplace(A, B, tid);
    uint4* dst = tmp1 + (size_t)n * NV;
    for (int i = tid; i < NV; i += NT) {
        float f[8];
#pragma unroll
        for (int j = 0; j < 8; ++j) f[j] = A[8 * i + j];
        dst[i] = pack8(f);
    }
}

// tmp2 = smooth(preA + (a3/norm) * sum_k w_k * tmp1[knn_k]) as bf16
__global__ __launch_bounds__(NT) void k_mid(
        const int* __restrict__ knn, const float* __restrict__ dist,
        const float* __restrict__ alpha, const uint4* __restrict__ tmp1,
        const uint4* __restrict__ preA, uint4* __restrict__ tmp2, int K) {
    __shared__ alignas(16) float A[ASZ];
    __shared__ alignas(16) float B[BSZ];
    __shared__ float s_w[8];
    const int n = blockIdx.x;
    const int tid = threadIdx.x;
    if (tid < K) s_w[tid] = expf(-dist[n * K + tid] * (1.0f / 200.0f));
    __syncthreads();
    float norm = 0.0f;
    for (int k = 0; k < K; ++k) norm += s_w[k];
    const float sc = alpha[3] / norm;

    const uint4* ptr[8];
    float wk[8];
    for (int k = 0; k < K; ++k) {
        ptr[k] = tmp1 + (size_t)knn[n * K + k] * NV;
        wk[k] = s_w[k];
    }
    const uint4* pre = preA + (size_t)n * NV;
    for (int i = tid; i < NV; i += NT) {
        float f[8], acc[8], g[8];
        unpack8(pre[i], f);
#pragma unroll
        for (int j = 0; j < 8; ++j) acc[j] = 0.0f;
#pragma unroll 8
        for (int k = 0; k < K; ++k) {
            unpack8(ptr[k][i], g);
#pragma unroll
            for (int j = 0; j < 8; ++j) acc[j] = fmaf(wk[k], g[j], acc[j]);
        }
#pragma unroll
        for (int j = 0; j < 8; ++j) A[8 * i + j] = fmaf(sc, acc[j], f[j]);
    }
    smooth_inplace(A, B, tid);
    uint4* dst = tmp2 + (size_t)n * NV;
    for (int i = tid; i < NV; i += NT) {
        float f[8];
#pragma unroll
        for (int j = 0; j < 8; ++j) f[j] = A[8 * i + j];
        dst[i] = pack8(f);
    }
}

// out = (a5/norm) * sum_k w_k * tmp2[knn_k]   (fp32 output)
__global__ __launch_bounds__(NT) void k_out(
        const int* __restrict__ knn, const float* __restrict__ dist,
        const float* __restrict__ alpha, const uint4* __restrict__ tmp2,
        float* __restrict__ out, int K) {
    __shared__ float s_w[8];
    const int n = blockIdx.x;
    const int tid = threadIdx.x;
    if (tid < K) s_w[tid] = expf(-dist[n * K + tid] * (1.0f / 200.0f));
    __syncthreads();
    float norm = 0.0f;
    for (int k = 0; k < K; ++k) norm += s_w[k];
    const float sc = alpha[5] / norm;

    const uint4* ptr[8];
    float wk[8];
    for (int k = 0; k < K; ++k) {
        ptr[k] = tmp2 + (size_t)knn[n * K + k] * NV;
        wk[k] = s_w[k];
    }
    float* dst = out + (size_t)n * L3;
    for (int i = tid; i < NV; i += NT) {
        float acc[8], g[8];
#pragma unroll
        for (int j = 0; j < 8; ++j) acc[j] = 0.0f;
#pragma unroll 8
        for (int k = 0; k < K; ++k) {
            unpack8(ptr[k][i], g);
#pragma unroll
            for (int j = 0; j < 8; ++j) acc[j] = fmaf(wk[k], g[j], acc[j]);
        }
        int base = 8 * i;
#pragma unroll
        for (int j = 0; j < 8; ++j)
            if (base + j < L3) dst[base + j] = sc * acc[j];
    }
}

extern "C" void kernel_launch(void* const* d_in, const int* in_sizes, int n_in,
                              void* d_out, int out_size, void* d_ws, size_t ws_size,
                              hipStream_t stream) {
    const float* cost  = (const float*)d_in[0];
    const int*   knn   = (const int*)d_in[1];
    const float* dist  = (const float*)d_in[2];
    const float* alpha = (const float*)d_in[3];
    float* out = (float*)d_out;

    const int N = in_sizes[0] / L3;
    int K = in_sizes[1] / N;
    if (K > 8) K = 8;

    // workspace: three bf16 volumes arrays, each N*SP bf16 = N*SP*2 bytes
    uint4* tmp1 = (uint4*)d_ws;
    uint4* tmp2 = tmp1 + (size_t)N * NV;
    uint4* preA = tmp2 + (size_t)N * NV;

    k_smooth1<<<N, NT, 0, stream>>>(cost, alpha, tmp1, preA);
    k_mid<<<N, NT, 0, stream>>>(knn, dist, alpha, tmp1, preA, tmp2, K);
    k_out<<<N, NT, 0, stream>>>(knn, dist, alpha, tmp2, out, K);
}

// Round 4
// 336.386 us; speedup vs baseline: 1.7526x; 1.0696x over previous
//
#include <hip/hip_runtime.h>
#include <math.h>

#define L3 2197            // 13^3
#define SP 2200            // bf16 elems per padded volume (4400 B, 16B-aligned)
#define NV (SP / 8)        // 275 uint4 chunks of 8 bf16
#define NTS 320            // threads for smooth kernels (>=289 pencils, 5 waves)
#define NTO 256            // threads for k_out

// Single in-place LDS buffer: peak stage size 17^3
#define SSZ 4913

typedef unsigned int u32;

// round-to-nearest-even bf16 pack of two floats -> one u32 (lo = a, hi = b)
__device__ __forceinline__ u32 pack2bf(float a, float b) {
    u32 ua = __float_as_uint(a);
    u32 ub = __float_as_uint(b);
    ua = (ua + 0x7fffu + ((ua >> 16) & 1u)) >> 16;
    ub = (ub + 0x7fffu + ((ub >> 16) & 1u)) & 0xffff0000u;
    return ua | ub;
}

__device__ __forceinline__ void unpack8(uint4 v, float* f) {
    f[0] = __uint_as_float(v.x << 16);
    f[1] = __uint_as_float(v.x & 0xffff0000u);
    f[2] = __uint_as_float(v.y << 16);
    f[3] = __uint_as_float(v.y & 0xffff0000u);
    f[4] = __uint_as_float(v.z << 16);
    f[5] = __uint_as_float(v.z & 0xffff0000u);
    f[6] = __uint_as_float(v.w << 16);
    f[7] = __uint_as_float(v.w & 0xffff0000u);
}

__device__ __forceinline__ uint4 pack8(const float* f) {
    uint4 v;
    v.x = pack2bf(f[0], f[1]);
    v.y = pack2bf(f[2], f[3]);
    v.z = pack2bf(f[4], f[5]);
    v.w = pack2bf(f[6], f[7]);
    return v;
}

// Sliding clamped max-of-3: in x[13], out o[17].
__device__ __forceinline__ void maxpool_row(const float* x, float* o) {
    float p[12];
#pragma unroll
    for (int i = 0; i < 12; ++i) p[i] = fmaxf(x[i], x[i + 1]);
    o[0] = x[0];
    o[1] = x[0];
    o[2] = p[0];
#pragma unroll
    for (int j = 3; j <= 13; ++j) o[j] = fmaxf(p[j - 3], x[j - 1]);
    o[14] = p[11];
    o[15] = x[12];
    o[16] = x[12];
}

// Two stacked avgpool3 == 5-tap triangle [1,2,3,2,1]/9 per axis.
__device__ __forceinline__ void tri_row(const float* y, float* o, float scale) {
#pragma unroll
    for (int c = 0; c < 13; ++c) {
        float s = fmaf(2.0f, y[c + 1], y[c]);
        s = fmaf(3.0f, y[c + 2], s);
        s = fmaf(2.0f, y[c + 3], s);
        o[c] = (s + y[c + 4]) * scale;
    }
}

// S holds (13,13,13) input (c fastest); on return S[0..2196] = smooth(S).
// In-place single-buffer: each stage loads its pencil to regs, barriers, writes.
// Stage shapes: 2197 -> 2873 -> 3757 -> 4913 -> 3757 -> 2873 -> 2197 (peak 17^3)
__device__ void smooth_single(float* S, int tid) {
    __syncthreads();   // make fill visible
    // M1 along c: (13,13,13) -> (13,13,17); 169 row pencils
    {
        const bool act = tid < 169;
        float x[13], o[17];
        if (act) {
            const float* src = S + tid * 13;
#pragma unroll
            for (int i = 0; i < 13; ++i) x[i] = src[i];
            maxpool_row(x, o);
        }
        __syncthreads();
        if (act) {
            float* d = S + tid * 17;
#pragma unroll
            for (int i = 0; i < 17; ++i) d[i] = o[i];
        }
        __syncthreads();
    }
    // M2 along b: (13,13,17) -> (13,17,17); 221 pencils (a,c)
    {
        const bool act = tid < 221;
        const int a = tid / 17, c = tid % 17;
        float x[13], o[17];
        if (act) {
            const float* src = S + a * 221 + c;
#pragma unroll
            for (int i = 0; i < 13; ++i) x[i] = src[i * 17];
            maxpool_row(x, o);
        }
        __syncthreads();
        if (act) {
            float* d = S + a * 289 + c;
#pragma unroll
            for (int i = 0; i < 17; ++i) d[i * 17] = o[i];
        }
        __syncthreads();
    }
    // M3 along a: (13,17,17) -> (17,17,17); own-column in-place, no mid-barrier
    if (tid < 289) {
        float x[13], o[17];
        const float* src = S + tid;
#pragma unroll
        for (int i = 0; i < 13; ++i) x[i] = src[i * 289];
        maxpool_row(x, o);
        float* d = S + tid;
#pragma unroll
        for (int i = 0; i < 17; ++i) d[i * 289] = o[i];
    }
    __syncthreads();
    // C1 along c: (17,17,17) -> (17,17,13); 289 row pencils
    {
        const bool act = tid < 289;
        float y[17], o[13];
        if (act) {
            const float* src = S + tid * 17;
#pragma unroll
            for (int i = 0; i < 17; ++i) y[i] = src[i];
            tri_row(y, o, 1.0f);
        }
        __syncthreads();
        if (act) {
            float* d = S + tid * 13;
#pragma unroll
            for (int i = 0; i < 13; ++i) d[i] = o[i];
        }
        __syncthreads();
    }
    // C2 along b: (17,17,13) -> (17,13,13); 221 pencils (a,c)
    {
        const bool act = tid < 221;
        const int a = tid / 13, c = tid % 13;
        float y[17], o[13];
        if (act) {
            const float* src = S + a * 221 + c;
#pragma unroll
            for (int i = 0; i < 17; ++i) y[i] = src[i * 13];
            tri_row(y, o, 1.0f);
        }
        __syncthreads();
        if (act) {
            float* d = S + a * 169 + c;
#pragma unroll
            for (int i = 0; i < 13; ++i) d[i * 13] = o[i];
        }
        __syncthreads();
    }
    // C3 along a: (17,13,13) -> (13,13,13); own-column in-place, scale 1/729
    if (tid < 169) {
        float y[17], o[13];
        const float* src = S + tid;
#pragma unroll
        for (int i = 0; i < 17; ++i) y[i] = src[i * 169];
        tri_row(y, o, 1.0f / 729.0f);
        float* d = S + tid;
#pragma unroll
        for (int i = 0; i < 13; ++i) d[i * 169] = o[i];
    }
    __syncthreads();
}

// tmp1 = smooth(affine) as bf16; preA = a4 + a2*affine as bf16
__global__ __launch_bounds__(NTS) void k_smooth1(
        const float* __restrict__ cost, const float* __restrict__ alpha,
        uint4* __restrict__ tmp1, uint4* __restrict__ preA) {
    __shared__ alignas(16) float S[SSZ];
    const int n = blockIdx.x;
    const int tid = threadIdx.x;
    const float a0 = alpha[0], a1 = alpha[1], a2 = alpha[2], a4 = alpha[4];
    const float* src = cost + (size_t)n * L3;
    for (int i = tid; i < L3; i += NTS) S[i] = fmaf(a0, src[i], a1);
    if (tid < SP - L3) S[L3 + tid] = 0.0f;   // pad for pack loop
    __syncthreads();
    uint4* pre = preA + (size_t)n * NV;
    if (tid < NV) {
        float f[8];
#pragma unroll
        for (int j = 0; j < 8; ++j) f[j] = fmaf(a2, S[8 * tid + j], a4);
        pre[tid] = pack8(f);
    }
    smooth_single(S, tid);
    uint4* dst = tmp1 + (size_t)n * NV;
    if (tid < NV) {
        float f[8];
        const int base = 8 * tid;
#pragma unroll
        for (int j = 0; j < 8; ++j) f[j] = (base + j < L3) ? S[base + j] : 0.0f;
        dst[tid] = pack8(f);
    }
}

// tmp2 = smooth(preA + (a3/norm) * sum_k w_k * tmp1[knn_k]) as bf16
__global__ __launch_bounds__(NTS) void k_mid(
        const int* __restrict__ knn, const float* __restrict__ dist,
        const float* __restrict__ alpha, const uint4* __restrict__ tmp1,
        const uint4* __restrict__ preA, uint4* __restrict__ tmp2, int K) {
    __shared__ alignas(16) float S[SSZ];
    __shared__ float s_w[8];
    const int n = blockIdx.x;
    const int tid = threadIdx.x;
    if (tid < K) s_w[tid] = expf(-dist[n * K + tid] * (1.0f / 200.0f));
    __syncthreads();
    float norm = 0.0f;
    for (int k = 0; k < K; ++k) norm += s_w[k];
    const float sc = alpha[3] / norm;

    const uint4* ptr[8];
    float wk[8];
    for (int k = 0; k < K; ++k) {
        ptr[k] = tmp1 + (size_t)knn[n * K + k] * NV;
        wk[k] = s_w[k];
    }
    const uint4* pre = preA + (size_t)n * NV;
    if (tid < NV) {
        float f[8], acc[8], g[8];
        unpack8(pre[tid], f);
#pragma unroll
        for (int j = 0; j < 8; ++j) acc[j] = 0.0f;
#pragma unroll 8
        for (int k = 0; k < K; ++k) {
            unpack8(ptr[k][tid], g);
#pragma unroll
            for (int j = 0; j < 8; ++j) acc[j] = fmaf(wk[k], g[j], acc[j]);
        }
#pragma unroll
        for (int j = 0; j < 8; ++j) S[8 * tid + j] = fmaf(sc, acc[j], f[j]);
    }
    smooth_single(S, tid);
    uint4* dst = tmp2 + (size_t)n * NV;
    if (tid < NV) {
        float f[8];
        const int base = 8 * tid;
#pragma unroll
        for (int j = 0; j < 8; ++j) f[j] = (base + j < L3) ? S[base + j] : 0.0f;
        dst[tid] = pack8(f);
    }
}

// out = (a5/norm) * sum_k w_k * tmp2[knn_k]   (fp32 output)
__global__ __launch_bounds__(NTO) void k_out(
        const int* __restrict__ knn, const float* __restrict__ dist,
        const float* __restrict__ alpha, const uint4* __restrict__ tmp2,
        float* __restrict__ out, int K) {
    __shared__ float s_w[8];
    const int n = blockIdx.x;
    const int tid = threadIdx.x;
    if (tid < K) s_w[tid] = expf(-dist[n * K + tid] * (1.0f / 200.0f));
    __syncthreads();
    float norm = 0.0f;
    for (int k = 0; k < K; ++k) norm += s_w[k];
    const float sc = alpha[5] / norm;

    const uint4* ptr[8];
    float wk[8];
    for (int k = 0; k < K; ++k) {
        ptr[k] = tmp2 + (size_t)knn[n * K + k] * NV;
        wk[k] = s_w[k];
    }
    float* dst = out + (size_t)n * L3;
    for (int i = tid; i < NV; i += NTO) {
        float acc[8], g[8];
#pragma unroll
        for (int j = 0; j < 8; ++j) acc[j] = 0.0f;
#pragma unroll 8
        for (int k = 0; k < K; ++k) {
            unpack8(ptr[k][i], g);
#pragma unroll
            for (int j = 0; j < 8; ++j) acc[j] = fmaf(wk[k], g[j], acc[j]);
        }
        const int base = 8 * i;
#pragma unroll
        for (int j = 0; j < 8; ++j)
            if (base + j < L3) dst[base + j] = sc * acc[j];
    }
}

extern "C" void kernel_launch(void* const* d_in, const int* in_sizes, int n_in,
                              void* d_out, int out_size, void* d_ws, size_t ws_size,
                              hipStream_t stream) {
    const float* cost  = (const float*)d_in[0];
    const int*   knn   = (const int*)d_in[1];
    const float* dist  = (const float*)d_in[2];
    const float* alpha = (const float*)d_in[3];
    float* out = (float*)d_out;

    const int N = in_sizes[0] / L3;
    int K = in_sizes[1] / N;
    if (K > 8) K = 8;

    // workspace: three bf16 volume arrays, each N*SP bf16 (N*SP*2 bytes)
    uint4* tmp1 = (uint4*)d_ws;
    uint4* tmp2 = tmp1 + (size_t)N * NV;
    uint4* preA = tmp2 + (size_t)N * NV;

    k_smooth1<<<N, NTS, 0, stream>>>(cost, alpha, tmp1, preA);
    k_mid<<<N, NTS, 0, stream>>>(knn, dist, alpha, tmp1, preA, tmp2, K);
    k_out<<<N, NTO, 0, stream>>>(knn, dist, alpha, tmp2, out, K);
}